// Round 3
// baseline (225.453 us; speedup 1.0000x reference)
//
#include <hip/hip_runtime.h>

// CustomPuzzleLoss: loss1 = mean|p - t|, loss2 = 0.1 * dup_count/B over 5x5
// grids (rows+cols, exact float equality, "seen earlier" semantics),
// +1000 if any p outside [0.5, 5.5]. Output: single float scalar.
//
// R3: R2 showed the kernel is latency-bound (80 us even when inputs are fully
// L3-resident; VGPR=24 -> compiler serialized the staging loads). Fix: stage
// preds via __builtin_amdgcn_global_load_lds (async global->LDS, zero VGPR
// cost, 5x1KB in flight per wave), issue targets as 5 independent int4
// register loads before the barrier so they overlap the DMA.

#define BLOCK 320                                // 5 waves
#define GRIDS_PER_BLOCK 256
#define ELEMS_PER_BLOCK (GRIDS_PER_BLOCK * 25)   // 6400 floats = 25600 B
#define VEC_ITERS (ELEMS_PER_BLOCK / 4 / BLOCK)  // 1600/320 = 5 exactly
#define NWAVES (BLOCK / 64)
#define CHUNK_FLOATS 256                         // 1 KB per global_load_lds instr

#define GLOBAL_AS(p) ((__attribute__((address_space(1))) void*)(p))
#define LDS_AS(p)    ((__attribute__((address_space(3))) void*)(p))

__device__ __forceinline__ int grid_dups(const float* __restrict__ g) {
    int ldup = 0;
    // rows: element j is a dup if equal to any earlier k<j in its row
    #pragma unroll
    for (int r = 0; r < 5; ++r) {
        const float a = g[r*5+0], b = g[r*5+1], c = g[r*5+2],
                    d = g[r*5+3], e = g[r*5+4];
        ldup += (int)(b == a);
        ldup += (int)((c == a) | (c == b));
        ldup += (int)((d == a) | (d == b) | (d == c));
        ldup += (int)((e == a) | (e == b) | (e == c) | (e == d));
    }
    // cols: same on the transposed grid
    #pragma unroll
    for (int q = 0; q < 5; ++q) {
        const float a = g[q +  0], b = g[q +  5], c = g[q + 10],
                    d = g[q + 15], e = g[q + 20];
        ldup += (int)(b == a);
        ldup += (int)((c == a) | (c == b));
        ldup += (int)((d == a) | (d == b) | (d == c));
        ldup += (int)((e == a) | (e == b) | (e == c) | (e == d));
    }
    return ldup;
}

__global__ __launch_bounds__(BLOCK) void puzzle_main(
    const float* __restrict__ preds, const int* __restrict__ tgts,
    long long n_total,
    float* __restrict__ blk_sum, int* __restrict__ blk_dup,
    int* __restrict__ blk_oob)
{
    __shared__ float lds[ELEMS_PER_BLOCK];   // 25600 B, contiguous (DMA layout)
    __shared__ float s_sum[NWAVES];
    __shared__ int   s_dup[NWAVES];
    __shared__ int   s_oob[NWAVES];

    const int tid  = threadIdx.x;
    const int lane = tid & 63;
    const int wv   = tid >> 6;
    const long long base = (long long)blockIdx.x * ELEMS_PER_BLOCK;
    const long long rem = n_total - base;
    const int nelem = (int)(rem < ELEMS_PER_BLOCK ? rem : ELEMS_PER_BLOCK);

    float lsum = 0.0f;
    int   loob = 0;
    int   ldup = 0;

    if (nelem == ELEMS_PER_BLOCK) {
        const float* src = preds + base;
        const int4* __restrict__ t4 = (const int4*)(tgts + base);

        // --- async DMA: each wave stages 5 x 1KB of preds into LDS.
        // Zero VGPR cost; all 5 in flight; drained by vmcnt(0) at the barrier.
        #pragma unroll
        for (int j = 0; j < 5; ++j) {
            const int off = (wv * 5 + j) * CHUNK_FLOATS;  // float index, 1KB chunks
            __builtin_amdgcn_global_load_lds(GLOBAL_AS(src + off + lane * 4),
                                             LDS_AS(&lds[off]), 16, 0, 0);
        }

        // --- targets: 5 independent int4 register loads, overlap the DMA ---
        int4 t[VEC_ITERS];
        #pragma unroll
        for (int k = 0; k < VEC_ITERS; ++k) t[k] = t4[tid + k * BLOCK];

        __syncthreads();   // waits vmcnt(0): DMA + t-loads complete

        // --- loss1 + oob from LDS preds + register targets ---
        const float4* lds4 = reinterpret_cast<const float4*>(lds);
        #pragma unroll
        for (int k = 0; k < VEC_ITERS; ++k) {
            const float4 p = lds4[tid + k * BLOCK];
            lsum += fabsf(p.x - (float)t[k].x);
            lsum += fabsf(p.y - (float)t[k].y);
            lsum += fabsf(p.z - (float)t[k].z);
            lsum += fabsf(p.w - (float)t[k].w);
            loob |= (int)((p.x < 0.5f) | (p.x > 5.5f));
            loob |= (int)((p.y < 0.5f) | (p.y > 5.5f));
            loob |= (int)((p.z < 0.5f) | (p.z > 5.5f));
            loob |= (int)((p.w < 0.5f) | (p.w > 5.5f));
        }

        // --- dup pass: one thread per 5x5 grid; stride 25 (odd) -> 2-way
        // bank aliasing only (free on gfx950) ---
        if (tid < GRIDS_PER_BLOCK) ldup = grid_dups(&lds[tid * 25]);
    } else {
        // --- tail block fallback (n % 6400 != 0; not hit for n = 26214400) ---
        const int nvec = nelem >> 2;
        const float4* __restrict__ p4g = (const float4*)(preds + base);
        const int4*   __restrict__ t4g = (const int4*)(tgts + base);
        float4* lds4w = reinterpret_cast<float4*>(lds);
        for (int i = tid; i < nvec; i += BLOCK) {
            const float4 p = p4g[i];
            const int4   t = t4g[i];
            lsum += fabsf(p.x - (float)t.x) + fabsf(p.y - (float)t.y) +
                    fabsf(p.z - (float)t.z) + fabsf(p.w - (float)t.w);
            loob |= (int)((p.x < 0.5f) | (p.x > 5.5f));
            loob |= (int)((p.y < 0.5f) | (p.y > 5.5f));
            loob |= (int)((p.z < 0.5f) | (p.z > 5.5f));
            loob |= (int)((p.w < 0.5f) | (p.w > 5.5f));
            lds4w[i] = p;
        }
        for (int i = (nvec << 2) + tid; i < nelem; i += BLOCK) {
            const float p = preds[base + i];
            const int   t = tgts[base + i];
            lsum += fabsf(p - (float)t);
            loob |= (int)((p < 0.5f) | (p > 5.5f));
            lds[i] = p;
        }
        __syncthreads();
        const int ngrids = nelem / 25;
        if (tid < ngrids) ldup = grid_dups(&lds[tid * 25]);
    }

    // --- block reduction: wave shuffle then cross-wave via LDS ---
    #pragma unroll
    for (int off = 32; off > 0; off >>= 1) {
        lsum += __shfl_down(lsum, off, 64);
        ldup += __shfl_down(ldup, off, 64);
        loob |= __shfl_down(loob, off, 64);
    }
    if (lane == 0) { s_sum[wv] = lsum; s_dup[wv] = ldup; s_oob[wv] = loob; }
    __syncthreads();
    if (tid == 0) {
        float bs = 0.0f; int bd = 0, bo = 0;
        #pragma unroll
        for (int w = 0; w < NWAVES; ++w) { bs += s_sum[w]; bd += s_dup[w]; bo |= s_oob[w]; }
        blk_sum[blockIdx.x] = bs;
        blk_dup[blockIdx.x] = bd;
        blk_oob[blockIdx.x] = bo;
    }
}

#define FBLOCK 256
#define FNWAVES (FBLOCK / 64)

__global__ __launch_bounds__(FBLOCK) void puzzle_final(
    const float* __restrict__ blk_sum, const int* __restrict__ blk_dup,
    const int* __restrict__ blk_oob, int nblocks,
    long long n_total, long long batch, float* __restrict__ out)
{
    __shared__ double s_sum[FNWAVES];
    __shared__ int    s_dup[FNWAVES];
    __shared__ int    s_oob[FNWAVES];

    double lsum = 0.0;
    int ldup = 0, loob = 0;
    for (int i = threadIdx.x; i < nblocks; i += FBLOCK) {
        lsum += (double)blk_sum[i];
        ldup += blk_dup[i];
        loob |= blk_oob[i];
    }
    #pragma unroll
    for (int off = 32; off > 0; off >>= 1) {
        lsum += __shfl_down(lsum, off, 64);
        ldup += __shfl_down(ldup, off, 64);
        loob |= __shfl_down(loob, off, 64);
    }
    const int wave = threadIdx.x >> 6;
    if ((threadIdx.x & 63) == 0) { s_sum[wave] = lsum; s_dup[wave] = ldup; s_oob[wave] = loob; }
    __syncthreads();
    if (threadIdx.x == 0) {
        double bs = 0.0; int bd = 0, bo = 0;
        #pragma unroll
        for (int w = 0; w < FNWAVES; ++w) { bs += s_sum[w]; bd += s_dup[w]; bo |= s_oob[w]; }
        const float loss1 = (float)(bs / (double)n_total);
        const float loss2 = (float)((double)bd * 0.1 / (double)batch);
        out[0] = loss1 + loss2 + (bo ? 1000.0f : 0.0f);
    }
}

extern "C" void kernel_launch(void* const* d_in, const int* in_sizes, int n_in,
                              void* d_out, int out_size, void* d_ws, size_t ws_size,
                              hipStream_t stream) {
    const float* preds = (const float*)d_in[0];
    const int*   tgts  = (const int*)d_in[1];
    float* out = (float*)d_out;

    const long long n = (long long)in_sizes[0];
    const long long batch = n / 25;
    const int nblocks = (int)((n + ELEMS_PER_BLOCK - 1) / ELEMS_PER_BLOCK);

    // workspace layout: [float sums | int dups | int oobs], each nblocks long
    float* blk_sum = (float*)d_ws;
    int*   blk_dup = (int*)(blk_sum + nblocks);
    int*   blk_oob = (int*)(blk_dup + nblocks);

    puzzle_main<<<nblocks, BLOCK, 0, stream>>>(preds, tgts, n,
                                               blk_sum, blk_dup, blk_oob);
    puzzle_final<<<1, FBLOCK, 0, stream>>>(blk_sum, blk_dup, blk_oob,
                                           nblocks, n, batch, out);
}

// Round 4
// 222.551 us; speedup vs baseline: 1.0130x; 1.0130x over previous
//
#include <hip/hip_runtime.h>

// CustomPuzzleLoss: loss1 = mean|p - t|, loss2 = 0.1 * dup_count/B over 5x5
// grids (rows+cols, exact float equality, "seen earlier" semantics),
// +1000 if any p outside [0.5, 5.5]. Output: single float scalar.
//
// R4: R3 post-mortem — compiler sank the int4 target loads past the barrier
// (VGPR=20) and serialized them; kernel stayed latency-bound at 1.3 TB/s.
// Fix: DMA BOTH preds and targets into LDS via global_load_lds. Zero VGPRs
// in the staging path -> nothing to sink; each wave issues 10 independent
// 1 KB DMAs back-to-back (51.2 KB in flight per block, 3 blocks/CU), drained
// once by the barrier's vmcnt(0). All consumption is LDS reads.

#define BLOCK 320                                // 5 waves
#define GRIDS_PER_BLOCK 256
#define ELEMS_PER_BLOCK (GRIDS_PER_BLOCK * 25)   // 6400 floats = 25600 B
#define VEC_ITERS (ELEMS_PER_BLOCK / 4 / BLOCK)  // 1600/320 = 5 exactly
#define NWAVES (BLOCK / 64)
#define CHUNK_FLOATS 256                         // 1 KB per global_load_lds

#define GLOBAL_AS(p) ((__attribute__((address_space(1))) void*)(p))
#define LDS_AS(p)    ((__attribute__((address_space(3))) void*)(p))

__device__ __forceinline__ int grid_dups(const float* __restrict__ g) {
    int ldup = 0;
    // rows: element j is a dup if equal to any earlier k<j in its row
    #pragma unroll
    for (int r = 0; r < 5; ++r) {
        const float a = g[r*5+0], b = g[r*5+1], c = g[r*5+2],
                    d = g[r*5+3], e = g[r*5+4];
        ldup += (int)(b == a);
        ldup += (int)((c == a) | (c == b));
        ldup += (int)((d == a) | (d == b) | (d == c));
        ldup += (int)((e == a) | (e == b) | (e == c) | (e == d));
    }
    // cols: same on the transposed grid
    #pragma unroll
    for (int q = 0; q < 5; ++q) {
        const float a = g[q +  0], b = g[q +  5], c = g[q + 10],
                    d = g[q + 15], e = g[q + 20];
        ldup += (int)(b == a);
        ldup += (int)((c == a) | (c == b));
        ldup += (int)((d == a) | (d == b) | (d == c));
        ldup += (int)((e == a) | (e == b) | (e == c) | (e == d));
    }
    return ldup;
}

__global__ __launch_bounds__(BLOCK) void puzzle_main(
    const float* __restrict__ preds, const int* __restrict__ tgts,
    long long n_total,
    float* __restrict__ blk_sum, int* __restrict__ blk_dup,
    int* __restrict__ blk_oob)
{
    __shared__ float lds_p[ELEMS_PER_BLOCK];   // 25600 B (DMA layout, contiguous)
    __shared__ int   lds_t[ELEMS_PER_BLOCK];   // 25600 B
    __shared__ float s_sum[NWAVES];
    __shared__ int   s_dup[NWAVES];
    __shared__ int   s_oob[NWAVES];

    const int tid  = threadIdx.x;
    const int lane = tid & 63;
    const int wv   = tid >> 6;
    const long long base = (long long)blockIdx.x * ELEMS_PER_BLOCK;
    const long long rem = n_total - base;
    const int nelem = (int)(rem < ELEMS_PER_BLOCK ? rem : ELEMS_PER_BLOCK);

    float lsum = 0.0f;
    int   loob = 0;
    int   ldup = 0;

    if (nelem == ELEMS_PER_BLOCK) {
        const float* srcp = preds + base;
        const int*   srct = tgts  + base;

        // --- async DMA: each wave stages 5x1KB of preds AND 5x1KB of targets.
        // 10 independent wave-instrs, zero VGPR cost, all in flight at once;
        // drained by the single vmcnt(0) the barrier emits.
        #pragma unroll
        for (int j = 0; j < 5; ++j) {
            const int off = (wv * 5 + j) * CHUNK_FLOATS;
            __builtin_amdgcn_global_load_lds(GLOBAL_AS(srcp + off + lane * 4),
                                             LDS_AS(&lds_p[off]), 16, 0, 0);
        }
        #pragma unroll
        for (int j = 0; j < 5; ++j) {
            const int off = (wv * 5 + j) * CHUNK_FLOATS;
            __builtin_amdgcn_global_load_lds(GLOBAL_AS(srct + off + lane * 4),
                                             LDS_AS(&lds_t[off]), 16, 0, 0);
        }
        __syncthreads();   // vmcnt(0): all 50 KB of DMA complete

        // --- loss1 + oob: pure LDS reads (ds_read_b128), no global latency ---
        const float4* __restrict__ p4l = reinterpret_cast<const float4*>(lds_p);
        const int4*   __restrict__ t4l = reinterpret_cast<const int4*>(lds_t);
        #pragma unroll
        for (int k = 0; k < VEC_ITERS; ++k) {
            const float4 p = p4l[tid + k * BLOCK];
            const int4   t = t4l[tid + k * BLOCK];
            lsum += fabsf(p.x - (float)t.x);
            lsum += fabsf(p.y - (float)t.y);
            lsum += fabsf(p.z - (float)t.z);
            lsum += fabsf(p.w - (float)t.w);
            loob |= (int)((p.x < 0.5f) | (p.x > 5.5f));
            loob |= (int)((p.y < 0.5f) | (p.y > 5.5f));
            loob |= (int)((p.z < 0.5f) | (p.z > 5.5f));
            loob |= (int)((p.w < 0.5f) | (p.w > 5.5f));
        }

        // --- dup pass: one thread per 5x5 grid; stride 25 (odd) -> 2-way
        // bank aliasing only (free on gfx950) ---
        if (tid < GRIDS_PER_BLOCK) ldup = grid_dups(&lds_p[tid * 25]);
    } else {
        // --- tail block fallback (not hit: 26214400 % 6400 == 0) ---
        const int nvec = nelem >> 2;
        const float4* __restrict__ p4g = (const float4*)(preds + base);
        const int4*   __restrict__ t4g = (const int4*)(tgts + base);
        float4* lds4w = reinterpret_cast<float4*>(lds_p);
        for (int i = tid; i < nvec; i += BLOCK) {
            const float4 p = p4g[i];
            const int4   t = t4g[i];
            lsum += fabsf(p.x - (float)t.x) + fabsf(p.y - (float)t.y) +
                    fabsf(p.z - (float)t.z) + fabsf(p.w - (float)t.w);
            loob |= (int)((p.x < 0.5f) | (p.x > 5.5f));
            loob |= (int)((p.y < 0.5f) | (p.y > 5.5f));
            loob |= (int)((p.z < 0.5f) | (p.z > 5.5f));
            loob |= (int)((p.w < 0.5f) | (p.w > 5.5f));
            lds4w[i] = p;
        }
        for (int i = (nvec << 2) + tid; i < nelem; i += BLOCK) {
            const float p = preds[base + i];
            const int   t = tgts[base + i];
            lsum += fabsf(p - (float)t);
            loob |= (int)((p < 0.5f) | (p > 5.5f));
            lds_p[i] = p;
        }
        __syncthreads();
        const int ngrids = nelem / 25;
        if (tid < ngrids) ldup = grid_dups(&lds_p[tid * 25]);
    }

    // --- block reduction: wave shuffle then cross-wave via LDS ---
    #pragma unroll
    for (int off = 32; off > 0; off >>= 1) {
        lsum += __shfl_down(lsum, off, 64);
        ldup += __shfl_down(ldup, off, 64);
        loob |= __shfl_down(loob, off, 64);
    }
    if (lane == 0) { s_sum[wv] = lsum; s_dup[wv] = ldup; s_oob[wv] = loob; }
    __syncthreads();
    if (tid == 0) {
        float bs = 0.0f; int bd = 0, bo = 0;
        #pragma unroll
        for (int w = 0; w < NWAVES; ++w) { bs += s_sum[w]; bd += s_dup[w]; bo |= s_oob[w]; }
        blk_sum[blockIdx.x] = bs;
        blk_dup[blockIdx.x] = bd;
        blk_oob[blockIdx.x] = bo;
    }
}

#define FBLOCK 256
#define FNWAVES (FBLOCK / 64)

__global__ __launch_bounds__(FBLOCK) void puzzle_final(
    const float* __restrict__ blk_sum, const int* __restrict__ blk_dup,
    const int* __restrict__ blk_oob, int nblocks,
    long long n_total, long long batch, float* __restrict__ out)
{
    __shared__ double s_sum[FNWAVES];
    __shared__ int    s_dup[FNWAVES];
    __shared__ int    s_oob[FNWAVES];

    double lsum = 0.0;
    int ldup = 0, loob = 0;
    for (int i = threadIdx.x; i < nblocks; i += FBLOCK) {
        lsum += (double)blk_sum[i];
        ldup += blk_dup[i];
        loob |= blk_oob[i];
    }
    #pragma unroll
    for (int off = 32; off > 0; off >>= 1) {
        lsum += __shfl_down(lsum, off, 64);
        ldup += __shfl_down(ldup, off, 64);
        loob |= __shfl_down(loob, off, 64);
    }
    const int wave = threadIdx.x >> 6;
    if ((threadIdx.x & 63) == 0) { s_sum[wave] = lsum; s_dup[wave] = ldup; s_oob[wave] = loob; }
    __syncthreads();
    if (threadIdx.x == 0) {
        double bs = 0.0; int bd = 0, bo = 0;
        #pragma unroll
        for (int w = 0; w < FNWAVES; ++w) { bs += s_sum[w]; bd += s_dup[w]; bo |= s_oob[w]; }
        const float loss1 = (float)(bs / (double)n_total);
        const float loss2 = (float)((double)bd * 0.1 / (double)batch);
        out[0] = loss1 + loss2 + (bo ? 1000.0f : 0.0f);
    }
}

extern "C" void kernel_launch(void* const* d_in, const int* in_sizes, int n_in,
                              void* d_out, int out_size, void* d_ws, size_t ws_size,
                              hipStream_t stream) {
    const float* preds = (const float*)d_in[0];
    const int*   tgts  = (const int*)d_in[1];
    float* out = (float*)d_out;

    const long long n = (long long)in_sizes[0];
    const long long batch = n / 25;
    const int nblocks = (int)((n + ELEMS_PER_BLOCK - 1) / ELEMS_PER_BLOCK);

    // workspace layout: [float sums | int dups | int oobs], each nblocks long
    float* blk_sum = (float*)d_ws;
    int*   blk_dup = (int*)(blk_sum + nblocks);
    int*   blk_oob = (int*)(blk_dup + nblocks);

    puzzle_main<<<nblocks, BLOCK, 0, stream>>>(preds, tgts, n,
                                               blk_sum, blk_dup, blk_oob);
    puzzle_final<<<1, FBLOCK, 0, stream>>>(blk_sum, blk_dup, blk_oob,
                                           nblocks, n, batch, out);
}

// Round 5
// 221.879 us; speedup vs baseline: 1.0161x; 1.0030x over previous
//
#include <hip/hip_runtime.h>

// CustomPuzzleLoss: loss1 = mean|p - t|, loss2 = 0.1 * dup_count/B over 5x5
// grids (rows+cols, exact float equality, "seen earlier" semantics),
// +1000 if any p outside [0.5, 5.5]. Output: single float scalar.
//
// R5: R1-R4 all plateaued at ~80 us regardless of staging style -> bottleneck
// is workgroup churn (4096 short blocks, ~51 WG/us) + barrier-phase-locked
// block lifetimes, not the loads. Restructure: 512 persistent-ish blocks,
// WAVE-PRIVATE tiles (1600 floats = 64 grids, one grid per lane), DMA into a
// private LDS slice, per-wave s_waitcnt vmcnt(0) -- NO __syncthreads in the
// hot loop. Each lane computes loss1 + oob(min/max) + dups from registers.

#define BLOCK 256
#define WAVES_PER_BLOCK 4
#define TILE 1600                 // floats per wave-tile = 64 grids * 25
#define NBLOCKS 512
#define NWAVES WAVES_PER_BLOCK

#define GLOBAL_AS(p) ((__attribute__((address_space(1))) void*)(p))
#define LDS_AS(p)    ((__attribute__((address_space(3))) void*)(p))

// dup count for one 5x5 grid held in registers p[25]
__device__ __forceinline__ int grid_dups_reg(const float* p) {
    int ldup = 0;
    #pragma unroll
    for (int r = 0; r < 5; ++r) {           // rows
        const float a = p[r*5+0], b = p[r*5+1], c = p[r*5+2],
                    d = p[r*5+3], e = p[r*5+4];
        ldup += (int)(b == a);
        ldup += (int)((c == a) | (c == b));
        ldup += (int)((d == a) | (d == b) | (d == c));
        ldup += (int)((e == a) | (e == b) | (e == c) | (e == d));
    }
    #pragma unroll
    for (int q = 0; q < 5; ++q) {           // cols
        const float a = p[q+0], b = p[q+5], c = p[q+10],
                    d = p[q+15], e = p[q+20];
        ldup += (int)(b == a);
        ldup += (int)((c == a) | (c == b));
        ldup += (int)((d == a) | (d == b) | (d == c));
        ldup += (int)((e == a) | (e == b) | (e == c) | (e == d));
    }
    return ldup;
}

__global__ __launch_bounds__(BLOCK) void puzzle_main(
    const float* __restrict__ preds, const int* __restrict__ tgts,
    long long n_total,
    float* __restrict__ blk_sum, int* __restrict__ blk_dup,
    int* __restrict__ blk_oob)
{
    __shared__ float lds_p[WAVES_PER_BLOCK * TILE];   // 25600 B
    __shared__ int   lds_t[WAVES_PER_BLOCK * TILE];   // 25600 B
    __shared__ float s_sum[NWAVES];
    __shared__ int   s_dup[NWAVES];
    __shared__ int   s_oob[NWAVES];

    const int tid  = threadIdx.x;
    const int lane = tid & 63;
    const int wv   = tid >> 6;

    const long long total_tiles = n_total / TILE;
    const int total_waves = gridDim.x * WAVES_PER_BLOCK;
    const int gwave = blockIdx.x * WAVES_PER_BLOCK + wv;

    float* __restrict__ wp = &lds_p[wv * TILE];
    int*   __restrict__ wt = &lds_t[wv * TILE];

    float lsum = 0.0f;
    int   ldup = 0;
    float mn =  1e30f;
    float mx = -1e30f;

    for (long long t = gwave; t < total_tiles; t += total_waves) {
        const float* srcp = preds + t * TILE;
        const int*   srct = tgts  + t * TILE;

        // wave-private async DMA: 6x(16B/lane) + 1x(4B/lane) per array.
        // Zero VGPR cost; 12.8 KB in flight per wave.
        __builtin_amdgcn_sched_barrier(0);
        #pragma unroll
        for (int c = 0; c < 6; ++c)
            __builtin_amdgcn_global_load_lds(GLOBAL_AS(srcp + c*256 + lane*4),
                                             LDS_AS(wp + c*256), 16, 0, 0);
        __builtin_amdgcn_global_load_lds(GLOBAL_AS(srcp + 1536 + lane),
                                         LDS_AS(wp + 1536), 4, 0, 0);
        #pragma unroll
        for (int c = 0; c < 6; ++c)
            __builtin_amdgcn_global_load_lds(GLOBAL_AS(srct + c*256 + lane*4),
                                             LDS_AS(wt + c*256), 16, 0, 0);
        __builtin_amdgcn_global_load_lds(GLOBAL_AS(srct + 1536 + lane),
                                         LDS_AS(wt + 1536), 4, 0, 0);

        __builtin_amdgcn_s_waitcnt(0x0F70);   // vmcnt(0), no lgkm/exp wait
        __builtin_amdgcn_sched_barrier(0);    // pin LDS reads after the wait

        // lane owns grid `lane`: 25 consecutive floats (stride 25 across
        // lanes = 2-way LDS bank aliasing, free on gfx950)
        const float* __restrict__ g  = wp + lane * 25;
        const int*   __restrict__ ti = wt + lane * 25;

        float p[25];
        #pragma unroll
        for (int j = 0; j < 25; ++j) p[j] = g[j];

        #pragma unroll
        for (int j = 0; j < 25; ++j) {
            lsum += fabsf(p[j] - (float)ti[j]);
            mn = fminf(mn, p[j]);
            mx = fmaxf(mx, p[j]);
        }
        ldup += grid_dups_reg(p);
    }

    // ragged tail (n % TILE != 0; n is always a multiple of 25): last wave
    // reads straight from global, one grid per lane.
    const long long rem = n_total - total_tiles * TILE;
    if (rem > 0 && gwave == total_waves - 1) {
        const int ngrids = (int)(rem / 25);
        if (lane < ngrids) {
            const float* srcp = preds + total_tiles * TILE + (long long)lane * 25;
            const int*   srct = tgts  + total_tiles * TILE + (long long)lane * 25;
            float p[25];
            #pragma unroll
            for (int j = 0; j < 25; ++j) p[j] = srcp[j];
            #pragma unroll
            for (int j = 0; j < 25; ++j) {
                lsum += fabsf(p[j] - (float)srct[j]);
                mn = fminf(mn, p[j]);
                mx = fmaxf(mx, p[j]);
            }
            ldup += grid_dups_reg(p);
        }
    }

    // wave reduction
    #pragma unroll
    for (int off = 32; off > 0; off >>= 1) {
        lsum += __shfl_down(lsum, off, 64);
        ldup += __shfl_down(ldup, off, 64);
        mn = fminf(mn, __shfl_down(mn, off, 64));
        mx = fmaxf(mx, __shfl_down(mx, off, 64));
    }
    if (lane == 0) {
        s_sum[wv] = lsum;
        s_dup[wv] = ldup;
        s_oob[wv] = (int)((mn < 0.5f) | (mx > 5.5f));
    }
    __syncthreads();
    if (tid == 0) {
        float bs = 0.0f; int bd = 0, bo = 0;
        #pragma unroll
        for (int w = 0; w < NWAVES; ++w) { bs += s_sum[w]; bd += s_dup[w]; bo |= s_oob[w]; }
        blk_sum[blockIdx.x] = bs;
        blk_dup[blockIdx.x] = bd;
        blk_oob[blockIdx.x] = bo;
    }
}

#define FBLOCK 256
#define FNWAVES (FBLOCK / 64)

__global__ __launch_bounds__(FBLOCK) void puzzle_final(
    const float* __restrict__ blk_sum, const int* __restrict__ blk_dup,
    const int* __restrict__ blk_oob, int nblocks,
    long long n_total, long long batch, float* __restrict__ out)
{
    __shared__ double s_sum[FNWAVES];
    __shared__ int    s_dup[FNWAVES];
    __shared__ int    s_oob[FNWAVES];

    double lsum = 0.0;
    int ldup = 0, loob = 0;
    for (int i = threadIdx.x; i < nblocks; i += FBLOCK) {
        lsum += (double)blk_sum[i];
        ldup += blk_dup[i];
        loob |= blk_oob[i];
    }
    #pragma unroll
    for (int off = 32; off > 0; off >>= 1) {
        lsum += __shfl_down(lsum, off, 64);
        ldup += __shfl_down(ldup, off, 64);
        loob |= __shfl_down(loob, off, 64);
    }
    const int wave = threadIdx.x >> 6;
    if ((threadIdx.x & 63) == 0) { s_sum[wave] = lsum; s_dup[wave] = ldup; s_oob[wave] = loob; }
    __syncthreads();
    if (threadIdx.x == 0) {
        double bs = 0.0; int bd = 0, bo = 0;
        #pragma unroll
        for (int w = 0; w < FNWAVES; ++w) { bs += s_sum[w]; bd += s_dup[w]; bo |= s_oob[w]; }
        const float loss1 = (float)(bs / (double)n_total);
        const float loss2 = (float)((double)bd * 0.1 / (double)batch);
        out[0] = loss1 + loss2 + (bo ? 1000.0f : 0.0f);
    }
}

extern "C" void kernel_launch(void* const* d_in, const int* in_sizes, int n_in,
                              void* d_out, int out_size, void* d_ws, size_t ws_size,
                              hipStream_t stream) {
    const float* preds = (const float*)d_in[0];
    const int*   tgts  = (const int*)d_in[1];
    float* out = (float*)d_out;

    const long long n = (long long)in_sizes[0];
    const long long batch = n / 25;

    // workspace layout: [float sums | int dups | int oobs], each NBLOCKS long
    float* blk_sum = (float*)d_ws;
    int*   blk_dup = (int*)(blk_sum + NBLOCKS);
    int*   blk_oob = (int*)(blk_dup + NBLOCKS);

    puzzle_main<<<NBLOCKS, BLOCK, 0, stream>>>(preds, tgts, n,
                                               blk_sum, blk_dup, blk_oob);
    puzzle_final<<<1, FBLOCK, 0, stream>>>(blk_sum, blk_dup, blk_oob,
                                           NBLOCKS, n, batch, out);
}